// Round 1
// baseline (16.425 us; speedup 1.0000x reference)
//
#include <hip/hip_runtime.h>

#define NGT 64
#define NUM_CLASSES_F 80.0f
#define INF_F 100000000.0f
#define RADIUS_F 1.5f

__global__ __launch_bounds__(256) void fcos_match_kernel(
    const float* __restrict__ locations,      // (L,2)
    const float* __restrict__ strides_per_loc,// (L,)
    const float* __restrict__ soi,            // (L,2)
    const float* __restrict__ anchors,        // (L,4)
    const float* __restrict__ gt_boxes,       // (B,G,4)
    const int*   __restrict__ gt_classes,     // (B,G)
    float* __restrict__ out,                  // cls (B*L) | reg (B*L*4) | deltas (B*L*4)
    int L, int B)
{
    const int b = blockIdx.y;
    const int i = blockIdx.x * blockDim.x + threadIdx.x;

    __shared__ float4 sbox[NGT];
    __shared__ float  sarea[NGT];
    __shared__ float  sccx[NGT];
    __shared__ float  sccy[NGT];
    __shared__ float  sclsf[NGT];

    if (threadIdx.x < NGT) {
        const int j = threadIdx.x;
        float4 bx = reinterpret_cast<const float4*>(gt_boxes)[b * NGT + j];
        sbox[j]  = bx;
        sarea[j] = (bx.z - bx.x) * (bx.w - bx.y);
        sccx[j]  = (bx.x + bx.z) * 0.5f;
        sccy[j]  = (bx.y + bx.w) * 0.5f;
        sclsf[j] = (float)gt_classes[b * NGT + j];
    }
    __syncthreads();

    if (i >= L) return;

    const float2 xy = reinterpret_cast<const float2*>(locations)[i];
    const float  x  = xy.x, y = xy.y;
    const float  rad = strides_per_loc[i] * RADIUS_F;
    const float2 lohi = reinterpret_cast<const float2*>(soi)[i];
    const float  lo = lohi.x, hi = lohi.y;

    float minv = INF_F;
    int   ind  = 0;

    #pragma unroll
    for (int j = 0; j < NGT; ++j) {
        const float4 bx = sbox[j];
        const float l  = x - bx.x;
        const float t  = y - bx.y;
        const float r  = bx.z - x;
        const float bb = bx.w - y;

        const float xmin = fmaxf(sccx[j] - rad, bx.x);
        const float ymin = fmaxf(sccy[j] - rad, bx.y);
        const float xmax = fminf(sccx[j] + rad, bx.z);
        const float ymax = fminf(sccy[j] + rad, bx.w);

        const float cb = fminf(fminf(x - xmin, y - ymin),
                               fminf(xmax - x, ymax - y));
        const float mx = fmaxf(fmaxf(l, t), fmaxf(r, bb));

        const bool valid = (cb > 0.0f) && (mx >= lo) && (mx <= hi);
        const float v = valid ? sarea[j] : INF_F;
        if (v < minv) { minv = v; ind = j; }   // strict < -> first-occurrence argmin
    }

    const float4 mb = sbox[ind];
    const float l  = x - mb.x;
    const float t  = y - mb.y;
    const float r  = mb.z - x;
    const float bb = mb.w - y;

    // cls
    const float cls = (minv == INF_F) ? NUM_CLASSES_F : sclsf[ind];
    out[(size_t)b * L + i] = cls;

    // reg targets
    const size_t reg_base = (size_t)B * L + ((size_t)b * L + i) * 4;
    out[reg_base + 0] = l;
    out[reg_base + 1] = t;
    out[reg_base + 2] = r;
    out[reg_base + 3] = bb;

    // deltas
    const float4 an = reinterpret_cast<const float4*>(anchors)[i];
    const float aw  = an.z - an.x;
    const float ah  = an.w - an.y;
    const float acx = an.x + 0.5f * aw;
    const float acy = an.y + 0.5f * ah;
    const float gw  = mb.z - mb.x;
    const float gh  = mb.w - mb.y;
    const float gcx = mb.x + 0.5f * gw;
    const float gcy = mb.y + 0.5f * gh;

    const size_t del_base = (size_t)B * L * 5 + ((size_t)b * L + i) * 4;
    out[del_base + 0] = (gcx - acx) / aw;
    out[del_base + 1] = (gcy - acy) / ah;
    out[del_base + 2] = logf(gw / aw);
    out[del_base + 3] = logf(gh / ah);
}

extern "C" void kernel_launch(void* const* d_in, const int* in_sizes, int n_in,
                              void* d_out, int out_size, void* d_ws, size_t ws_size,
                              hipStream_t stream) {
    const float* locations = (const float*)d_in[0];
    const float* strides   = (const float*)d_in[1];
    const float* soi       = (const float*)d_in[2];
    const float* anchors   = (const float*)d_in[3];
    const float* gt_boxes  = (const float*)d_in[4];
    const int*   gt_cls    = (const int*)d_in[5];
    float* out = (float*)d_out;

    const int L = in_sizes[1];            // strides_per_loc has L elements
    const int B = in_sizes[5] / NGT;      // gt_classes has B*G elements

    dim3 block(256);
    dim3 grid((L + 255) / 256, B);
    fcos_match_kernel<<<grid, block, 0, stream>>>(locations, strides, soi, anchors,
                                                  gt_boxes, gt_cls, out, L, B);
}